// Round 7
// baseline (41.442 us; speedup 1.0000x reference)
//
#include <hip/hip_runtime.h>
#include <math.h>

#define BB 4
#define LL 5
#define CC 64
#define HH 128
#define WW 256
#define NTOT 16
#define CG 8  // channels per block
#define HW (HH * WW)
#define NWG (BB * (CC / CG) * HH)  // 4096

struct Prep {
    int off0, off1;
    float wxa, wxb, wy0v, wy1v;
    const float* base;
};

__device__ __forceinline__ Prep prep_agent(
    const float* __restrict__ t, const float* __restrict__ x,
    int b, int l, int off, int cg, float gx, float gy)
{
    Prep p;
    const float* tm = t + (size_t)((b * LL * LL + l) * 16);
    const float m00 = tm[0];
    const float m01 = tm[1] * ((float)HH / (float)WW);
    const float m02 = tm[3] * (2.0f / (0.8f * (float)WW));
    const float m10 = tm[4] * ((float)WW / (float)HH);
    const float m11 = tm[5];
    const float m12 = tm[7] * (2.0f / (0.8f * (float)HH));
    const float sx  = 0.5f * (float)(WW - 1);
    const float sy  = 0.5f * (float)(HH - 1);
    const float a00 = m00 * sx, a01 = m01 * sx, a02 = (m02 + 1.0f) * sx;
    const float a10 = m10 * sy, a11 = m11 * sy, a12 = (m12 + 1.0f) * sy;

    const float ix = a00 * gx + a01 * gy + a02;
    const float iy = a10 * gx + a11 * gy + a12;

    const float x0f = floorf(ix), y0f = floorf(iy);
    const float wx1 = ix - x0f, wx0 = 1.0f - wx1;
    const float wy1 = iy - y0f, wy0 = 1.0f - wy1;
    const int x0 = (int)x0f, y0 = (int)y0f;

    const bool inx = (x0 >= 0) && (x0 <= WW - 2);
    p.wxa  = inx ? wx0 : ((x0 == -1)     ? wx1 : 0.0f);
    p.wxb  = inx ? wx1 : ((x0 == WW - 1) ? wx0 : 0.0f);
    p.wy0v = ((y0 >= 0)     && (y0 <= HH - 1))     ? wy0 : 0.0f;
    p.wy1v = ((y0 + 1 >= 0) && (y0 + 1 <= HH - 1)) ? wy1 : 0.0f;

    const int k  = min(max(x0, 0), WW - 2);
    const int r0 = min(max(y0,     0), HH - 1);
    const int r1 = min(max(y0 + 1, 0), HH - 1);
    p.off0 = r0 * WW + k;
    p.off1 = r1 * WW + k;

    const int n = off + l;  // always valid: off + rl <= NTOT
    p.base = x + ((size_t)n * CC + (size_t)cg * CG) * HW;
    return p;
}

__global__ __launch_bounds__(256) void maxfusion_kernel(
    const float* __restrict__ x,        // (NTOT, C, H, W)
    const int* __restrict__ record_len, // (B,)
    const float* __restrict__ t,        // (B, L, L, 4, 4)
    float* __restrict__ out)            // (B, C, H, W)
{
    // Balance-aware XCD swizzle (round 6 winner): xcd <- cg for ALL b.
    const int cg  = blockIdx.x % 8;
    const int idx = blockIdx.x / 8;
    const int h   = idx % HH;
    const int b   = idx / HH;
    const int w   = threadIdx.x;

    const int rl = record_len[b];
    int off = 0;
    #pragma unroll
    for (int j = 0; j < BB; ++j) off += (j < b) ? record_len[j] : 0;

    const float gx = -1.0f + 2.0f * (float)w / (float)(WW - 1);
    const float gy = -1.0f + 2.0f * (float)h / (float)(HH - 1);

    float maxv[CG];
    #pragma unroll
    for (int c = 0; c < CG; ++c) maxv[c] = -INFINITY;

    // Double-buffered register prefetch across the agent loop:
    // issue agent l+1's 16 loads BEFORE consuming agent l's registers, so
    // the consume's vmcnt wait covers only agent l while l+1's loads fly.
    float2 qA0[CG], qA1[CG], qB0[CG], qB1[CG];

    Prep pc = prep_agent(t, x, b, 0, off, cg, gx, gy);
    #pragma unroll
    for (int c = 0; c < CG; ++c) {
        const float* p = pc.base + (size_t)c * HW;
        qA0[c] = *reinterpret_cast<const float2*>(p + pc.off0);
        qA1[c] = *reinterpret_cast<const float2*>(p + pc.off1);
    }

    for (int l = 0; l < rl; ++l) {
        const bool has_next = (l + 1 < rl);
        Prep pn = pc;
        if (has_next) pn = prep_agent(t, x, b, l + 1, off, cg, gx, gy);

        if ((l & 1) == 0) {
            if (has_next) {
                #pragma unroll
                for (int c = 0; c < CG; ++c) {
                    const float* p = pn.base + (size_t)c * HW;
                    qB0[c] = *reinterpret_cast<const float2*>(p + pn.off0);
                    qB1[c] = *reinterpret_cast<const float2*>(p + pn.off1);
                }
            }
            #pragma unroll
            for (int c = 0; c < CG; ++c) {
                const float t0 = qA0[c].x * pc.wxa + qA0[c].y * pc.wxb;
                const float t1 = qA1[c].x * pc.wxa + qA1[c].y * pc.wxb;
                maxv[c] = fmaxf(maxv[c], t0 * pc.wy0v + t1 * pc.wy1v);
            }
        } else {
            if (has_next) {
                #pragma unroll
                for (int c = 0; c < CG; ++c) {
                    const float* p = pn.base + (size_t)c * HW;
                    qA0[c] = *reinterpret_cast<const float2*>(p + pn.off0);
                    qA1[c] = *reinterpret_cast<const float2*>(p + pn.off1);
                }
            }
            #pragma unroll
            for (int c = 0; c < CG; ++c) {
                const float t0 = qB0[c].x * pc.wxa + qB0[c].y * pc.wxb;
                const float t1 = qB1[c].x * pc.wxa + qB1[c].y * pc.wxb;
                maxv[c] = fmaxf(maxv[c], t0 * pc.wy0v + t1 * pc.wy1v);
            }
        }
        pc = pn;
    }

    float* ob = out + (((size_t)b * CC + (size_t)cg * CG) * HH + h) * WW + w;
    #pragma unroll
    for (int c = 0; c < CG; ++c)
        __builtin_nontemporal_store(maxv[c], ob + (size_t)c * HW);
}

extern "C" void kernel_launch(void* const* d_in, const int* in_sizes, int n_in,
                              void* d_out, int out_size, void* d_ws, size_t ws_size,
                              hipStream_t stream) {
    const float* x          = (const float*)d_in[0];
    const int*   record_len = (const int*)d_in[1];
    const float* t          = (const float*)d_in[2];
    float* out = (float*)d_out;

    maxfusion_kernel<<<NWG, 256, 0, stream>>>(x, record_len, t, out);
}

// Round 8
// 40.466 us; speedup vs baseline: 1.0241x; 1.0241x over previous
//
#include <hip/hip_runtime.h>
#include <math.h>

#define BB 4
#define LL 5
#define CC 64
#define HH 128
#define WW 256
#define NTOT 16
#define CG 4              // channels per block
#define HB 2              // output rows per block
#define HW (HH * WW)
#define NCG (CC / CG)     // 16
#define NHB (HH / HB)     // 64
#define NWG (BB * NCG * NHB)  // 4096

__global__ __launch_bounds__(256) void maxfusion_kernel(
    const float* __restrict__ x,        // (NTOT, C, H, W)
    const int* __restrict__ record_len, // (B,)
    const float* __restrict__ t,        // (B, L, L, 4, 4)
    float* __restrict__ out)            // (B, C, H, W)
{
    // Decode with balance-aware XCD swizzle (HW assigns XCD = blockIdx%8):
    //   xcd <- cg16 & 7  (each XCD owns 2 channel-groups across ALL b
    //                     -> per-XCD work = 2*sum(record_len), balanced)
    //   within an XCD, blocks walk (cg_hi, hb, b) with hb sequential for
    //   L2 row-streaming reuse.
    const int xcd_slot = blockIdx.x & 7;
    const int inner    = blockIdx.x >> 3;     // 0..511
    const int cg16     = xcd_slot + 8 * (inner & 1);  // 0..15
    const int rem      = inner >> 1;          // 0..255
    const int hb       = rem & 63;
    const int b        = rem >> 6;
    const int h0       = hb * HB;
    const int w        = threadIdx.x;

    const int rl = record_len[b];
    int off = 0;
    #pragma unroll
    for (int j = 0; j < BB; ++j) off += (j < b) ? record_len[j] : 0;

    const float gx = -1.0f + 2.0f * (float)w / (float)(WW - 1);

    float maxv[HB][CG];
    #pragma unroll
    for (int hh = 0; hh < HB; ++hh)
        #pragma unroll
        for (int c = 0; c < CG; ++c) maxv[hh][c] = -INFINITY;

    for (int l = 0; l < rl; ++l) {
        // t[b, 0, l] — block-uniform: scalar loads + SGPR math.
        const float* tm = t + (size_t)((b * LL * LL + l) * 16);
        const float m00 = tm[0];
        const float m01 = tm[1] * ((float)HH / (float)WW);
        const float m02 = tm[3] * (2.0f / (0.8f * (float)WW));
        const float m10 = tm[4] * ((float)WW / (float)HH);
        const float m11 = tm[5];
        const float m12 = tm[7] * (2.0f / (0.8f * (float)HH));
        const float sx  = 0.5f * (float)(WW - 1);
        const float sy  = 0.5f * (float)(HH - 1);
        const float a00 = m00 * sx, a01 = m01 * sx, a02 = (m02 + 1.0f) * sx;
        const float a10 = m10 * sy, a11 = m11 * sy, a12 = (m12 + 1.0f) * sy;

        float wxa[HB], wxb[HB], wy0v[HB], wy1v[HB];
        int off0[HB], off1[HB];
        #pragma unroll
        for (int hh = 0; hh < HB; ++hh) {
            const float gy = -1.0f + 2.0f * (float)(h0 + hh) / (float)(HH - 1);
            const float ix = a00 * gx + a01 * gy + a02;
            const float iy = a10 * gx + a11 * gy + a12;

            const float x0f = floorf(ix), y0f = floorf(iy);
            const float wx1 = ix - x0f, wx0 = 1.0f - wx1;
            const float wy1 = iy - y0f, wy0 = 1.0f - wy1;
            const int x0 = (int)x0f, y0 = (int)y0f;

            const bool inx = (x0 >= 0) && (x0 <= WW - 2);
            wxa[hh]  = inx ? wx0 : ((x0 == -1)     ? wx1 : 0.0f);
            wxb[hh]  = inx ? wx1 : ((x0 == WW - 1) ? wx0 : 0.0f);
            wy0v[hh] = ((y0 >= 0)     && (y0 <= HH - 1))     ? wy0 : 0.0f;
            wy1v[hh] = ((y0 + 1 >= 0) && (y0 + 1 <= HH - 1)) ? wy1 : 0.0f;

            const int k  = min(max(x0, 0), WW - 2);
            const int r0 = min(max(y0,     0), HH - 1);
            const int r1 = min(max(y0 + 1, 0), HH - 1);
            off0[hh] = r0 * WW + k;
            off1[hh] = r1 * WW + k;
        }

        const int n = off + l;  // always valid: off + rl <= NTOT
        const float* base = x + ((size_t)n * CC + (size_t)cg16 * CG) * HW;

        #pragma unroll
        for (int c = 0; c < CG; ++c) {
            const float* p = base + (size_t)c * HW;
            // Issue the h-pair's 4 row loads back-to-back: r1(h0) and
            // r0(h0+1) are usually the same row -> L1 hit / MSHR merge.
            const float2 qa0 = *reinterpret_cast<const float2*>(p + off0[0]);
            const float2 qa1 = *reinterpret_cast<const float2*>(p + off1[0]);
            const float2 qb0 = *reinterpret_cast<const float2*>(p + off0[1]);
            const float2 qb1 = *reinterpret_cast<const float2*>(p + off1[1]);

            const float ta0 = qa0.x * wxa[0] + qa0.y * wxb[0];
            const float ta1 = qa1.x * wxa[0] + qa1.y * wxb[0];
            maxv[0][c] = fmaxf(maxv[0][c], ta0 * wy0v[0] + ta1 * wy1v[0]);

            const float tb0 = qb0.x * wxa[1] + qb0.y * wxb[1];
            const float tb1 = qb1.x * wxa[1] + qb1.y * wxb[1];
            maxv[1][c] = fmaxf(maxv[1][c], tb0 * wy0v[1] + tb1 * wy1v[1]);
        }
    }

    float* ob = out + (((size_t)b * CC + (size_t)cg16 * CG) * HH + h0) * WW + w;
    #pragma unroll
    for (int c = 0; c < CG; ++c)
        #pragma unroll
        for (int hh = 0; hh < HB; ++hh)
            __builtin_nontemporal_store(maxv[hh][c],
                                        ob + (size_t)c * HW + (size_t)hh * WW);
}

extern "C" void kernel_launch(void* const* d_in, const int* in_sizes, int n_in,
                              void* d_out, int out_size, void* d_ws, size_t ws_size,
                              hipStream_t stream) {
    const float* x          = (const float*)d_in[0];
    const int*   record_len = (const int*)d_in[1];
    const float* t          = (const float*)d_in[2];
    float* out = (float*)d_out;

    maxfusion_kernel<<<NWG, 256, 0, stream>>>(x, record_len, t, out);
}